// Round 1
// baseline (73.525 us; speedup 1.0000x reference)
//
#include <hip/hip_runtime.h>
#include <math.h>

#define NUM_BODY 30
#define NPRED    32   // 30 body + 2 empty
#define BROWS    500

__global__ __launch_bounds__(256) void logic_model_kernel(
    const float* __restrict__ t,       // (B,1)
    const float* __restrict__ data,    // (B,30)
    const float* __restrict__ pi,      // (3,)
    const float* __restrict__ A,       // (2,32)
    const float* __restrict__ base_p,  // (1,)
    const float* __restrict__ fw,      // (2,)
    const float* __restrict__ prob,    // (4,)
    float* __restrict__ out)           // (B,3)
{
    const int b = blockIdx.x * blockDim.x + threadIdx.x;
    if (b >= BROWS) return;

    const float SIGMA = 0.1f, TEMP = 0.07f, TOL = 0.02f;

    const float base = base_p[0];
    const float tb   = t[b];

    // row of data_sample into registers
    float d[NUM_BODY];
    #pragma unroll
    for (int j = 0; j < NUM_BODY; ++j) d[j] = data[b * NUM_BODY + j];

    // log p*(z=0)
    out[b * 3 + 0] = logf(base) - tb * base + logf(pi[0]);

    const float p0 = prob[0], p1 = prob[1], p2 = prob[2], p3 = prob[3];

    // pair index tables: (0,1),(0,2),(1,2)
    const int PA[3] = {0, 0, 1};
    const int PB[3] = {1, 2, 2};

    #pragma unroll
    for (int f = 0; f < 2; ++f) {
        const float* Ai = A + f * NPRED;

        // indicator dot A (+ always-on empty preds) and max body time (mbt)
        float s   = Ai[30] + Ai[31];
        float mbt = 0.0f;                 // all products are >= 0
        #pragma unroll
        for (int j = 0; j < NUM_BODY; ++j) {
            const float ind = (d[j] <= tb) ? 1.0f : 0.0f;
            s   += ind * Ai[j];
            mbt  = fmaxf(mbt, ind * d[j] * Ai[j]);
        }
        float feat = expf(-fabsf(s - 3.0f) / SIGMA);

        // top-3 indices of Ai (descending value, lowest index on ties)
        int idx[3];
        unsigned used = 0u;
        #pragma unroll
        for (int k = 0; k < 3; ++k) {
            float best = -INFINITY;
            int   bi   = 0;
            for (int j = 0; j < NPRED; ++j) {
                if (used & (1u << j)) continue;
                if (Ai[j] > best) { best = Ai[j]; bi = j; }
            }
            idx[k] = bi;
            used |= (1u << bi);
        }
        // sort ascending (3-element network)
        if (idx[0] > idx[1]) { int tmp = idx[0]; idx[0] = idx[1]; idx[1] = tmp; }
        if (idx[1] > idx[2]) { int tmp = idx[1]; idx[1] = idx[2]; idx[2] = tmp; }
        if (idx[0] > idx[1]) { int tmp = idx[0]; idx[0] = idx[1]; idx[1] = tmp; }

        const bool v0 = idx[0] < NUM_BODY;
        const bool v1 = idx[1] < NUM_BODY;
        const bool v2 = idx[2] < NUM_BODY;
        const bool valid[3] = {v0, v1, v2};

        float num = 0.0f, den = 0.0f;
        float pvsum = 0.0f;
        #pragma unroll
        for (int p = 0; p < 3; ++p) {
            const bool pv = valid[PA[p]] && valid[PB[p]];
            const int  pa = min(idx[PA[p]], NUM_BODY - 1);
            const int  qb = min(idx[PB[p]], NUM_BODY - 1);
            const float td = d[pa] - d[qb];

            const float c0 = (td > TOL)        ? 1.0f : 0.0f;
            const float c1 = (fabsf(td) < TOL) ? 1.0f : 0.0f;
            const float c2 = (td < -TOL)       ? 1.0f : 0.0f;
            const float c3 = 1.0f - p0 * c0 - p1 * c1 - p2 * c2;

            // custom softmax over x = c_k * prob_k
            const float x0 = c0 * p0, x1 = c1 * p1, x2 = c2 * p2, x3 = c3 * p3;
            const float w0 = expf(x0 / TEMP), w1 = expf(x1 / TEMP);
            const float w2 = expf(x2 / TEMP), w3 = expf(x3 / TEMP);
            const float rrf = (w0 * x0 + w1 * x1 + w2 * x2 + w3 * x3)
                            / (w0 + w1 + w2 + w3);

            const float wp = pv ? expf(-rrf / TEMP) : 0.0f;
            num   += wp * rrf;
            den   += wp;
            pvsum += pv ? 1.0f : 0.0f;
        }
        float col = num / fmaxf(den, 1e-30f);
        if (!(pvsum > 0.0f)) col = 1.0f;

        feat *= col;

        const float sigm = 1.0f / (1.0f + expf(-(tb - mbt)));
        const float cur  = base + sigm * feat * fw[f];
        const float lps  = logf(cur) + (-tb * cur + sigm * (-mbt * base + mbt * cur))
                         + logf(pi[1 + f]);
        out[b * 3 + 1 + f] = lps;
    }
}

extern "C" void kernel_launch(void* const* d_in, const int* in_sizes, int n_in,
                              void* d_out, int out_size, void* d_ws, size_t ws_size,
                              hipStream_t stream) {
    const float* t    = (const float*)d_in[0];
    const float* data = (const float*)d_in[1];
    const float* pi   = (const float*)d_in[2];
    const float* A    = (const float*)d_in[3];
    const float* base = (const float*)d_in[4];
    const float* fw   = (const float*)d_in[5];
    const float* prob = (const float*)d_in[6];
    float* out = (float*)d_out;

    const int block = 256;
    const int grid  = (BROWS + block - 1) / block;  // 2 blocks
    logic_model_kernel<<<grid, block, 0, stream>>>(t, data, pi, A, base, fw, prob, out);
}

// Round 2
// 73.369 us; speedup vs baseline: 1.0021x; 1.0021x over previous
//
#include <hip/hip_runtime.h>
#include <math.h>

#define NUM_BODY 30
#define NPRED    32   // 30 body + 2 empty
#define BROWS    500

__global__ __launch_bounds__(64) void logic_model_kernel(
    const float* __restrict__ t,       // (B,1)
    const float* __restrict__ data,    // (B,30)
    const float* __restrict__ pi,      // (3,)
    const float* __restrict__ A,       // (2,32)
    const float* __restrict__ base_p,  // (1,)
    const float* __restrict__ fw,      // (2,)
    const float* __restrict__ prob,    // (4,)
    float* __restrict__ out)           // (B,3)
{
    const int b = blockIdx.x * blockDim.x + threadIdx.x;
    if (b >= BROWS) return;

    const float SIGMA = 0.1f, TEMP = 0.07f, TOL = 0.02f;

    const float base = base_p[0];
    const float tb   = t[b];
    const float p0 = prob[0], p1 = prob[1], p2 = prob[2], p3 = prob[3];

    const float* __restrict__ A0 = A;
    const float* __restrict__ A1 = A + NPRED;
    const float* __restrict__ row = data + b * NUM_BODY;

    // ---- single streaming pass over the row: indicator-dot and mbt for BOTH
    // formulas (no register array -> no scratch) ----
    float s0 = A0[30] + A0[31];
    float s1 = A1[30] + A1[31];
    float mbt0 = 0.0f, mbt1 = 0.0f;     // products are >= 0, so 0-init exact
    #pragma unroll
    for (int j = 0; j < NUM_BODY; ++j) {
        const float dj  = row[j];
        const float ind = (dj <= tb) ? 1.0f : 0.0f;
        const float idj = ind * dj;
        s0  += ind * A0[j];
        s1  += ind * A1[j];
        mbt0 = fmaxf(mbt0, idj * A0[j]);
        mbt1 = fmaxf(mbt1, idj * A1[j]);
    }

    // log p*(z=0)
    out[b * 3 + 0] = logf(base) - tb * base + logf(pi[0]);

    // pair index tables: (0,1),(0,2),(1,2)
    const int PA[3] = {0, 0, 1};
    const int PB[3] = {1, 2, 2};

    #pragma unroll
    for (int f = 0; f < 2; ++f) {
        const float* __restrict__ Ai = (f == 0) ? A0 : A1;
        const float s   = (f == 0) ? s0   : s1;
        const float mbt = (f == 0) ? mbt0 : mbt1;

        float feat = expf(-fabsf(s - 3.0f) / SIGMA);

        // top-3 indices of Ai (descending value, lowest index on ties)
        int idx[3];
        unsigned used = 0u;
        #pragma unroll
        for (int k = 0; k < 3; ++k) {
            float best = -INFINITY;
            int   bi   = 0;
            for (int j = 0; j < NPRED; ++j) {
                if (used & (1u << j)) continue;
                if (Ai[j] > best) { best = Ai[j]; bi = j; }
            }
            idx[k] = bi;
            used |= (1u << bi);
        }
        // sort ascending (3-element network) — static indexing only
        if (idx[0] > idx[1]) { int tmp = idx[0]; idx[0] = idx[1]; idx[1] = tmp; }
        if (idx[1] > idx[2]) { int tmp = idx[1]; idx[1] = idx[2]; idx[2] = tmp; }
        if (idx[0] > idx[1]) { int tmp = idx[0]; idx[0] = idx[1]; idx[1] = tmp; }

        const bool valid[3] = { idx[0] < NUM_BODY,
                                idx[1] < NUM_BODY,
                                idx[2] < NUM_BODY };

        float num = 0.0f, den = 0.0f;
        float pvsum = 0.0f;
        #pragma unroll
        for (int p = 0; p < 3; ++p) {
            const bool pv = valid[PA[p]] && valid[PB[p]];
            const int  pa = min(idx[PA[p]], NUM_BODY - 1);
            const int  qb = min(idx[PB[p]], NUM_BODY - 1);
            // direct global loads (L1/L2-hot); avoids runtime-indexed reg array
            const float td = row[pa] - row[qb];

            const float c0 = (td > TOL)        ? 1.0f : 0.0f;
            const float c1 = (fabsf(td) < TOL) ? 1.0f : 0.0f;
            const float c2 = (td < -TOL)       ? 1.0f : 0.0f;
            const float c3 = 1.0f - p0 * c0 - p1 * c1 - p2 * c2;

            // custom softmax over x = c_k * prob_k
            const float x0 = c0 * p0, x1 = c1 * p1, x2 = c2 * p2, x3 = c3 * p3;
            const float w0 = expf(x0 / TEMP), w1 = expf(x1 / TEMP);
            const float w2 = expf(x2 / TEMP), w3 = expf(x3 / TEMP);
            const float rrf = (w0 * x0 + w1 * x1 + w2 * x2 + w3 * x3)
                            / (w0 + w1 + w2 + w3);

            const float wp = pv ? expf(-rrf / TEMP) : 0.0f;
            num   += wp * rrf;
            den   += wp;
            pvsum += pv ? 1.0f : 0.0f;
        }
        float col = num / fmaxf(den, 1e-30f);
        if (!(pvsum > 0.0f)) col = 1.0f;

        feat *= col;

        const float sigm = 1.0f / (1.0f + expf(-(tb - mbt)));
        const float cur  = base + sigm * feat * fw[f];
        const float lps  = logf(cur) + (-tb * cur + sigm * (-mbt * base + mbt * cur))
                         + logf(pi[1 + f]);
        out[b * 3 + 1 + f] = lps;
    }
}

extern "C" void kernel_launch(void* const* d_in, const int* in_sizes, int n_in,
                              void* d_out, int out_size, void* d_ws, size_t ws_size,
                              hipStream_t stream) {
    const float* t    = (const float*)d_in[0];
    const float* data = (const float*)d_in[1];
    const float* pi   = (const float*)d_in[2];
    const float* A    = (const float*)d_in[3];
    const float* base = (const float*)d_in[4];
    const float* fw   = (const float*)d_in[5];
    const float* prob = (const float*)d_in[6];
    float* out = (float*)d_out;

    const int block = 64;
    const int grid  = (BROWS + block - 1) / block;  // 8 blocks, 1 wave each
    logic_model_kernel<<<grid, block, 0, stream>>>(t, data, pi, A, base, fw, prob, out);
}